// Round 7
// baseline (223.985 us; speedup 1.0000x reference)
//
#include <hip/hip_runtime.h>

// SpectralConv3d — algebra (verified by passing runs r0-r3, r6):
//   fftn axes (2,3,4) = (D2, D3, CIN); output zero for d1>=8
//   Weff[c,o,f3] = sum_ij w[c,o,i,j,f3];  DFT_c+mix+IDFT_c folds to T[c][f3][co]
//   ifftn norm 1/131072
//
// Round-7: rebalance. dur = ~160us fixed harness fills + ours (~62us).
// Move the 117MB zero-fill from k_final3 into k_dft2 (spare BW under its
// latency-bound phase) and fold k_weff into k_dft2's remaining 256 wgs.
//   k_dft2z : 2048 wgs: d2-DFT (x read once)  [r6 verbatim]
//             + wgs 0..1791: NT zero-fill one 64KB chunk of out[d1>=8]
//             + wgs 1792..2047: one k_weff chunk (verbatim body)
//   k_T     : 32 wgs x 1024, split reductions                   [r6 verbatim]
//   k_mix   : 256 wgs x 1024 (slab,f2): d3-DFT + T-mix -> s5    [r6 verbatim]
//   k_final3c: 256 wgs (d1<8 only): s5 slab in LDS, d3-IDFT, d2-IDFT, NT stores

#define PI2F 6.28318530717958647692f

typedef float vf4 __attribute__((ext_vector_type(4)));  // native vec for NT stores

// d2-DFT: S1[s][f2][d3][c] = sum_d2 x[b][d1][d2][d3][c] E64^-(f2 d2)
// 2048 wgs = (s=32) x (d3=64); 256 thr = (d2g=8) x (c=32); x read exactly once.
// Extra duty per wg (disjoint regions, no ordering hazards):
//   wg < 1792 : zero-fill out[b][8+..][..] chunk (64 KB NT stores)
//   wg >= 1792: Weff chunk e-block (wg-1792), as r6's k_weff.
__global__ void k_dft2z(const float* __restrict__ x,
                        const float* __restrict__ wr, const float* __restrict__ wi,
                        float2* __restrict__ Weff, float2* __restrict__ S1,
                        float* __restrict__ out) {
    __shared__ float2 tw64[64];
    __shared__ float2 P[2048];                    // [d2g*8+f2][c]  16 KB
    __shared__ float2 ls[256];                    // weff reduce (wg>=1792 only)
    int t = threadIdx.x;
    int gid = blockIdx.x;
    int d3 = gid & 63, s = gid >> 6;
    int b = s >> 3, d1 = s & 7;
    int c = t & 31, d2g = t >> 5;
    if (t < 64) {
        float sn, cs;
        __sincosf((PI2F / 64.f) * (float)t, &sn, &cs);
        tw64[t] = make_float2(cs, sn);
    }
    __syncthreads();
    const float* xp = x + (size_t)b * 8388608 + (size_t)d1 * 131072 + d3 * 32 + c;
    float2 acc[8];
    #pragma unroll
    for (int f2 = 0; f2 < 8; ++f2) acc[f2] = make_float2(0.f, 0.f);
    #pragma unroll
    for (int k = 0; k < 8; ++k) {
        int d2 = d2g * 8 + k;
        float v = xp[d2 * 2048];
        #pragma unroll
        for (int f2 = 0; f2 < 8; ++f2) {
            float2 e = tw64[(f2 * d2) & 63];
            acc[f2].x += v * e.x;
            acc[f2].y -= v * e.y;
        }
    }
    #pragma unroll
    for (int f2 = 0; f2 < 8; ++f2) P[(d2g * 8 + f2) * 32 + c] = acc[f2];
    __syncthreads();
    {
        int f2 = t >> 5, cc = t & 31;
        float2 a = make_float2(0.f, 0.f);
        #pragma unroll
        for (int g = 0; g < 8; ++g) {
            float2 v = P[(g * 8 + f2) * 32 + cc];
            a.x += v.x; a.y += v.y;
        }
        S1[(size_t)(s * 8 + f2) * 2048 + d3 * 32 + cc] = a;
    }
    // ---- extra duty ----
    if (gid < 1792) {
        // zero-fill: pair = (b,d1>=8), 8 sub-chunks of 16384 floats each
        int pair = gid >> 3, sub = gid & 7;
        int bb = pair / 56;
        int dd1 = 8 + (pair - bb * 56);           // 8..63
        float* zb = out + (size_t)bb * 8388608 + (size_t)dd1 * 131072 + sub * 16384;
        vf4* zp = (vf4*)zb;
        vf4 z = {0.f, 0.f, 0.f, 0.f};
        #pragma unroll
        for (int i = 0; i < 16; ++i)
            __builtin_nontemporal_store(z, zp + i * 256 + t);
    } else {
        // weff chunk (r6 k_weff body, blockIdx -> gid-1792)
        int eL = t & 31, ijg = t >> 5;
        int e = (gid - 1792) * 32 + eL;           // e = (fc*32+o)*8 + f3
        int base = (e >> 3) * 512 + (e & 7) + ijg * 64;   // ij stride 8 floats
        float sr = 0.f, si = 0.f;
        #pragma unroll
        for (int j = 0; j < 8; ++j) { sr += wr[base + j * 8]; si += wi[base + j * 8]; }
        ls[t] = make_float2(sr, si);
        __syncthreads();
        if (t < 32) {
            float2 a = ls[t];
            #pragma unroll
            for (int g = 1; g < 8; ++g) { float2 v = ls[g * 32 + t]; a.x += v.x; a.y += v.y; }
            Weff[(gid - 1792) * 32 + t] = a;
        }
    }
}

// T[c][f3][co] = sum_{fc,o} E32^-(fc c) Weff[fc][o][f3] E32^+(o co)
// 32 wgs (c) x 1024 thr; both 32-sums split 4-way.
__global__ void k_T(const float2* __restrict__ Weff, float2* __restrict__ T) {
    __shared__ float2 tw32[32];
    __shared__ float2 P[1024];
    __shared__ float2 A[256];
    int t = threadIdx.x;
    int c = blockIdx.x;
    if (t < 32) {
        float s, co_;
        __sincosf((PI2F / 32.f) * (float)t, &s, &co_);
        tw32[t] = make_float2(co_, s);
    }
    __syncthreads();
    {   // stage 1 partial: A[o][f3] = sum_fc Weff[fc][o*8+f3] * conj(tw32[fc*c])
        int g = t >> 8, rem = t & 255;            // rem = o*8+f3
        float2 acc = make_float2(0.f, 0.f);
        #pragma unroll
        for (int k = 0; k < 8; ++k) {
            int fc = g * 8 + k;
            float2 v = Weff[fc * 256 + rem];
            float2 e = tw32[(fc * c) & 31];
            acc.x += v.x * e.x + v.y * e.y;
            acc.y += v.y * e.x - v.x * e.y;
        }
        P[t] = acc;
    }
    __syncthreads();
    if (t < 256) {
        float2 a = P[t];
        #pragma unroll
        for (int g = 1; g < 4; ++g) { float2 v = P[g * 256 + t]; a.x += v.x; a.y += v.y; }
        A[t] = a;
    }
    __syncthreads();
    {   // stage 2 partial: T[c][f3][co] = sum_o A[o*8+f3] * tw32[o*co]
        int g = t >> 8, rem = t & 255;
        int f3 = rem >> 5, co = rem & 31;
        float2 acc = make_float2(0.f, 0.f);
        #pragma unroll
        for (int k = 0; k < 8; ++k) {
            int o = g * 8 + k;
            float2 v = A[o * 8 + f3];
            float2 e = tw32[(o * co) & 31];
            acc.x += v.x * e.x - v.y * e.y;
            acc.y += v.x * e.y + v.y * e.x;
        }
        P[t] = acc;
    }
    __syncthreads();
    if (t < 256) {
        float2 a = P[t];
        #pragma unroll
        for (int g = 1; g < 4; ++g) { float2 v = P[g * 256 + t]; a.x += v.x; a.y += v.y; }
        T[c * 256 + t] = a;
    }
}

// Mix: 256 wgs = (s,f2) x 1024 thr.
//   A: s2[f3][c]  = sum_d3 S1slab[d3][c] E64^-(f3 d3)   (split 4-way over d3)
//   B: s5[f3][co] = sum_c  s2 * T[c][f3][co]            (split 4-way over c)
// writes s5g[(s*8+f2)*256 + f3*32+co]  (512 KB total)
__global__ void k_mix(const float2* __restrict__ S1, const float2* __restrict__ T,
                      float2* __restrict__ s5g) {
    __shared__ float2 sl1[2048];   // [d3][c] 16 KB
    __shared__ float2 P[1024];
    __shared__ float2 s2[256];
    __shared__ float2 tw[64];
    int t = threadIdx.x;
    int gid = blockIdx.x;          // = s*8 + f2
    if (t < 64) {
        float sn, cs;
        __sincosf((PI2F / 64.f) * (float)t, &sn, &cs);
        tw[t] = make_float2(cs, sn);
    }
    {
        const float4* src = (const float4*)(S1 + (size_t)gid * 2048);
        ((float4*)sl1)[t] = src[t];
    }
    __syncthreads();
    {   // A partial
        int g = t >> 8, rem = t & 255;
        int f3 = rem >> 5, c = rem & 31;
        float2 a = make_float2(0.f, 0.f);
        #pragma unroll 4
        for (int k = 0; k < 16; ++k) {
            int d3 = g * 16 + k;
            float2 v = sl1[d3 * 32 + c];
            float2 e = tw[(f3 * d3) & 63];        // conj applied
            a.x += v.x * e.x + v.y * e.y;
            a.y += v.y * e.x - v.x * e.y;
        }
        P[t] = a;
    }
    __syncthreads();
    if (t < 256) {
        float2 a = P[t];
        #pragma unroll
        for (int g = 1; g < 4; ++g) { float2 v = P[g * 256 + t]; a.x += v.x; a.y += v.y; }
        s2[t] = a;
    }
    __syncthreads();
    {   // B partial
        int g = t >> 8, rem = t & 255;
        int f3 = rem >> 5, co = rem & 31;
        float2 a = make_float2(0.f, 0.f);
        #pragma unroll
        for (int k = 0; k < 8; ++k) {
            int cc = g * 8 + k;
            float2 v = s2[f3 * 32 + cc];
            float2 w = T[cc * 256 + f3 * 32 + co];
            a.x += v.x * w.x - v.y * w.y;
            a.y += v.x * w.y + v.y * w.x;
        }
        P[t] = a;
    }
    __syncthreads();
    if (t < 256) {
        float2 a = P[t];
        #pragma unroll
        for (int g = 1; g < 4; ++g) { float2 v = P[g * 256 + t]; a.x += v.x; a.y += v.y; }
        s5g[(size_t)gid * 256 + t] = a;
    }
}

// k_final3c: 256 wgs (d1<8 only): gid = s*8 + blk, s = b*8+d1.
//   ls5[f2][f3][co] <- s5 slab (16 KB = 1024 float4); d3-IDFT for own
//   8 d3 -> sq6[f2][d3r][co]; regs fragment; d2-IDFT; NT float4 stores.
__global__ void k_final3c(const float2* __restrict__ s5g, float* __restrict__ out) {
    __shared__ float2 ls5[2048];    // [f2][f3][co] 16 KB
    __shared__ float2 sq6[2048];    // [f2][d3r][co] 16 KB
    __shared__ float2 tw[64];
    int t = threadIdx.x;
    int gid = blockIdx.x;
    int blk = gid & 7;
    int s   = gid >> 3;             // b*8 + d1, d1 < 8
    int b   = s >> 3, d1 = s & 7;
    int co4 = t & 7;
    int d3r8 = (t >> 3) & 7;
    int d2q = t >> 6;               // wave-uniform
    float* obase = out + (size_t)b * 8388608 + (size_t)d1 * 131072
                 + (blk * 8 + d3r8) * 32 + co4 * 4;
    if (t < 64) {
        float sn, cs;
        __sincosf((PI2F / 64.f) * (float)t, &sn, &cs);
        tw[t] = make_float2(cs, sn);            // E^+
    }
    {   // stage s5 slab: 2048 float2 = 1024 float4
        const float4* src = (const float4*)(s5g + (size_t)s * 2048);
        float4* dst = (float4*)ls5;
        #pragma unroll
        for (int j = 0; j < 4; ++j) dst[t + j * 256] = src[t + j * 256];
    }
    __syncthreads();
    {   // d3-IDFT for this wg's 8 d3 values
        int co = t & 31, d3r = t >> 5;
        int d3 = blk * 8 + d3r;
        #pragma unroll
        for (int f2 = 0; f2 < 8; ++f2) {
            float2 a = make_float2(0.f, 0.f);
            #pragma unroll
            for (int f3 = 0; f3 < 8; ++f3) {
                float2 v = ls5[f2 * 256 + f3 * 32 + co];
                float2 e = tw[(f3 * d3) & 63];    // E^+
                a.x += v.x * e.x - v.y * e.y;
                a.y += v.x * e.y + v.y * e.x;
            }
            sq6[f2 * 256 + d3r * 32 + co] = a;
        }
    }
    __syncthreads();
    float2 v[8][4];
    #pragma unroll
    for (int f2 = 0; f2 < 8; ++f2) {
        #pragma unroll
        for (int k = 0; k < 4; ++k)
            v[f2][k] = sq6[f2 * 256 + d3r8 * 32 + co4 * 4 + k];
    }
    const float sc = 1.f / 131072.f;
    #pragma unroll 2
    for (int i = 0; i < 16; ++i) {
        int d2 = d2q * 16 + i;
        float rx = 0.f, ry = 0.f, rz = 0.f, rw = 0.f;
        #pragma unroll
        for (int f2 = 0; f2 < 8; ++f2) {
            float2 e = tw[(f2 * d2) & 63];      // wave-uniform broadcast
            rx += v[f2][0].x * e.x - v[f2][0].y * e.y;
            ry += v[f2][1].x * e.x - v[f2][1].y * e.y;
            rz += v[f2][2].x * e.x - v[f2][2].y * e.y;
            rw += v[f2][3].x * e.x - v[f2][3].y * e.y;
        }
        vf4 r = {rx * sc, ry * sc, rz * sc, rw * sc};
        __builtin_nontemporal_store(r, (vf4*)(obase + d2 * 2048));
    }
}

extern "C" void kernel_launch(void* const* d_in, const int* in_sizes, int n_in,
                              void* d_out, int out_size, void* d_ws, size_t ws_size,
                              hipStream_t stream) {
    const float* x  = (const float*)d_in[0];
    const float* wr = (const float*)d_in[1];
    const float* wi = (const float*)d_in[2];
    float* out = (float*)d_out;

    float2* Weff = (float2*)d_ws;            // 8192 float2
    float2* T    = Weff + 8192;              // 8192 float2
    float2* S1   = T + 8192;                 // 524288 float2 (4 MiB)
    float2* s5g  = S1 + 524288;              // 65536 float2 (512 KiB)

    k_dft2z  <<<2048, 256,  0, stream>>>(x, wr, wi, Weff, S1, out);
    k_T      <<<32,   1024, 0, stream>>>(Weff, T);
    k_mix    <<<256,  1024, 0, stream>>>(S1, T, s5g);
    k_final3c<<<256,  256,  0, stream>>>(s5g, out);
}